// Round 20
// baseline (206.899 us; speedup 1.0000x reference)
//
#include <hip/hip_runtime.h>
#include <hip/hip_bf16.h>
#include <math.h>

// Problem constants (fixed by the reference file)
#define T_TOK 2048
#define H_DIM 1024
#define I_DIM 2048
#define E_NUM 8
#define TOPK  2
#define P_MAX (T_TOK * TOPK)   // 4096 (token, k) pairs
#define MAX_SLOTS 40           // max 128-row slots: 4096/128 + 8
#define CONV_BLKS 128          // gemm1-fused w2-convert blocks

typedef __bf16 bf16_t;
typedef __attribute__((ext_vector_type(8))) __bf16 bf16x8;
typedef __attribute__((ext_vector_type(4))) float  f32x4;

// global_load_lds: per-lane GLOBAL address, wave-uniform LDS base; lane n
// writes lds_base + n*16 bytes (m104/m108).
#define GLOAD_LDS16(gptr, lptr)                                                   \
    __builtin_amdgcn_global_load_lds(                                             \
        (const __attribute__((address_space(1))) void*)(gptr),                    \
        (__attribute__((address_space(3))) void*)(lptr), 16, 0, 0)

__device__ inline f32x4 zero4() {
    f32x4 z; z[0] = 0.f; z[1] = 0.f; z[2] = 0.f; z[3] = 0.f; return z;
}

__device__ inline bf16x8 cvt8(f32x4 a, f32x4 b) {
    bf16x8 o;
    o[0] = (bf16_t)a[0]; o[1] = (bf16_t)a[1]; o[2] = (bf16_t)a[2]; o[3] = (bf16_t)a[3];
    o[4] = (bf16_t)b[0]; o[5] = (bf16_t)b[1]; o[6] = (bf16_t)b[2]; o[7] = (bf16_t)b[3];
    return o;
}

// ---------------------------------------------------------------- init
__global__ void init_kernel(int* counts, int* cursor) {
    int i = threadIdx.x;
    if (i < E_NUM) { counts[i] = 0; cursor[i] = 0; }
}

// ---------------------------------------------------------------- router
__global__ void router_kernel(const float* __restrict__ gating,
                              int* __restrict__ expert_id,
                              float* __restrict__ wt,
                              int* __restrict__ counts) {
    int t = blockIdx.x * blockDim.x + threadIdx.x;
    if (t >= T_TOK) return;
    float l[E_NUM];
    float m = -1e30f;
    #pragma unroll
    for (int e = 0; e < E_NUM; e++) { l[e] = gating[t * E_NUM + e]; m = fmaxf(m, l[e]); }
    float p[E_NUM];
    #pragma unroll
    for (int e = 0; e < E_NUM; e++) p[e] = __expf(l[e] - m);
    int i0 = 0; float p0 = p[0];
    #pragma unroll
    for (int e = 1; e < E_NUM; e++) if (p[e] > p0) { p0 = p[e]; i0 = e; }
    int i1 = -1; float p1 = -1.f;
    #pragma unroll
    for (int e = 0; e < E_NUM; e++) if (e != i0 && p[e] > p1) { p1 = p[e]; i1 = e; }
    float inv = 1.f / (p0 + p1);
    expert_id[t * 2 + 0] = i0; wt[t * 2 + 0] = p0 * inv;
    expert_id[t * 2 + 1] = i1; wt[t * 2 + 1] = p1 * inv;
    atomicAdd(&counts[i0], 1);
    atomicAdd(&counts[i1], 1);
}

// ---------------------------------------------------------------- scan + tile map
__global__ void scan_kernel(const int* __restrict__ counts,
                            int* __restrict__ offsets,
                            int* __restrict__ tile_e, int* __restrict__ tile_m0,
                            int* __restrict__ n_slots) {
    if (threadIdx.x != 0 || blockIdx.x != 0) return;
    int off = 0;
    for (int e = 0; e < E_NUM; e++) { offsets[e] = off; off += counts[e]; }
    offsets[E_NUM] = off;
    int s = 0;
    for (int e = 0; e < E_NUM; e++)
        for (int m0 = offsets[e]; m0 < offsets[e + 1]; m0 += 128) {
            tile_e[s] = e; tile_m0[s] = m0; s++;
        }
    *n_slots = s;
}

// ---------------------------------------------------------------- scatter
__global__ void scatter_kernel(const int* __restrict__ expert_id,
                               const float* __restrict__ wt,
                               const int* __restrict__ offsets,
                               int* __restrict__ cursor,
                               int* __restrict__ pair_token,
                               int* __restrict__ pair_dst,
                               float* __restrict__ pair_wt) {
    int t = blockIdx.x * blockDim.x + threadIdx.x;
    if (t >= T_TOK) return;
    #pragma unroll
    for (int k = 0; k < TOPK; k++) {
        int e = expert_id[t * 2 + k];
        int p = offsets[e] + atomicAdd(&cursor[e], 1);
        pair_token[p] = t;
        pair_dst[p]   = t * 2 + k;
        pair_wt[p]    = wt[t * 2 + k];
    }
}

// ---------------------------------------------------------------- f32 -> bf16 convert
// One launch for hidden + w1 (concatenated flat index; N0 is 16-divisible).
__global__ void convert_hw1_kernel(const float* __restrict__ hidden,
                                   const float* __restrict__ w1,
                                   bf16_t* __restrict__ hbf,
                                   bf16_t* __restrict__ w1bf) {
    const size_t N0 = (size_t)T_TOK * H_DIM;
    size_t g = (size_t)blockIdx.x * blockDim.x + threadIdx.x;
    size_t i = g * 16;
    const float* src; bf16_t* dst; size_t o;
    if (i < N0) { src = hidden; dst = hbf;  o = i; }
    else        { src = w1;     dst = w1bf; o = i - N0; }
    f32x4 v0 = *(const f32x4*)(src + o);
    f32x4 v1 = *(const f32x4*)(src + o + 4);
    f32x4 v2 = *(const f32x4*)(src + o + 8);
    f32x4 v3 = *(const f32x4*)(src + o + 12);
    *(bf16x8*)(dst + o)     = cvt8(v0, v1);
    *(bf16x8*)(dst + o + 8) = cvt8(v2, v3);
}

// ---------------------------------------------------------------- GEMM1 + SwiGLU (+ fused w2 convert)
// R8/R13 counted-vmcnt engine. Blocks [0, CONV_BLKS) convert w2 f32->bf16
// (grid-stride) and exit. Blocks >= CONV_BLKS run gemm1 items persistently.
// __launch_bounds__(512) WITHOUT waves-per-EU: (512,4) pinned the runtime
// occupancy target at 2 blocks/CU; resources (48KB LDS, 60 VGPR) allow 3.
__global__ __launch_bounds__(512)
void gemm1_kernel(const bf16_t* __restrict__ hbf,
                  const bf16_t* __restrict__ w1bf,
                  const float* __restrict__ w2,
                  bf16_t* __restrict__ w2bf,
                  const int* __restrict__ pair_token,
                  const int* __restrict__ offsets,
                  const int* __restrict__ tile_e,
                  const int* __restrict__ tile_m0,
                  const int* __restrict__ n_slots,
                  bf16_t* __restrict__ act) {
    __shared__ __align__(16) bf16_t sA[2][128][32];  // 16 KB
    __shared__ __align__(16) bf16_t sB[2][256][32];  // 32 KB

    int tid = threadIdx.x;

    if (blockIdx.x < CONV_BLKS) {   // ---- w2 convert role
        const size_t N2c = (size_t)E_NUM * H_DIM * I_DIM / 16;  // 16-elem chunks
        size_t stride = (size_t)CONV_BLKS * 512;
        for (size_t g = (size_t)blockIdx.x * 512 + tid; g < N2c; g += stride) {
            size_t i = g * 16;
            f32x4 v0 = *(const f32x4*)(w2 + i);
            f32x4 v1 = *(const f32x4*)(w2 + i + 4);
            f32x4 v2 = *(const f32x4*)(w2 + i + 8);
            f32x4 v3 = *(const f32x4*)(w2 + i + 12);
            *(bf16x8*)(w2bf + i)     = cvt8(v0, v1);
            *(bf16x8*)(w2bf + i + 8) = cvt8(v2, v3);
        }
        return;
    }

    int lane = tid & 63, w = tid >> 6;     // 8 waves
    int wm = w >> 2, wn = w & 3;           // 2M x 4N
    int l15 = lane & 15, lg = lane >> 4;
    int sr = lane >> 2, sg = lane & 3;     // staging sub-row / granule
    int gcol = (sg ^ (sr & 3)) * 8;        // inverse-swizzled SOURCE granule
    int rg   = (lg ^ (l15 & 3)) * 8;       // swizzled READ granule

    int nit = *n_slots * 16;
    for (int it = blockIdx.x - CONV_BLKS; it < nit; it += gridDim.x - CONV_BLKS) {
        int slot = it >> 4;
        int c0   = (it & 15) << 7;         // act cols [c0, c0+128)
        int e    = tile_e[slot];
        int m0   = tile_m0[slot];
        int mend = offsets[e + 1];
        const bf16_t* w1e = w1bf + (size_t)e * (2 * I_DIM) * H_DIM;

        // staging addresses (k0 added in loop)
        int parow = m0 + w * 16 + sr;
        int tok = (parow < mend) ? pair_token[parow] : 0;  // dummy, masked later
        const bf16_t* gA0 = hbf + (size_t)tok * H_DIM + gcol;
        int br0 = w * 32 + sr, br1 = br0 + 16;
        int wr0 = (br0 < 128) ? (c0 + br0) : (I_DIM + c0 + br0 - 128);
        int wr1 = (br1 < 128) ? (c0 + br1) : (I_DIM + c0 + br1 - 128);
        const bf16_t* gB0 = w1e + (size_t)wr0 * H_DIM + gcol;
        const bf16_t* gB1 = w1e + (size_t)wr1 * H_DIM + gcol;

        f32x4 acc[4][4];  // j=0,1 gate; j=2,3 up
        #pragma unroll
        for (int i = 0; i < 4; i++)
            #pragma unroll
            for (int j = 0; j < 4; j++) acc[i][j] = zero4();

        // prologue: stage K-step 0 into buf 0
        GLOAD_LDS16(gA0, &sA[0][w * 16][0]);
        GLOAD_LDS16(gB0, &sB[0][w * 32][0]);
        GLOAD_LDS16(gB1, &sB[0][w * 32 + 16][0]);

        for (int t = 0; t < 32; t++) {
            int cur = t & 1;
            if (t < 31) {
                int k0 = (t + 1) * 32;
                GLOAD_LDS16(gA0 + k0, &sA[cur ^ 1][w * 16][0]);
                GLOAD_LDS16(gB0 + k0, &sB[cur ^ 1][w * 32][0]);
                GLOAD_LDS16(gB1 + k0, &sB[cur ^ 1][w * 32 + 16][0]);
                asm volatile("s_waitcnt vmcnt(3)" ::: "memory");
            } else {
                asm volatile("s_waitcnt vmcnt(0)" ::: "memory");
            }
            __builtin_amdgcn_s_barrier();   // all waves' cur-tile loads landed

            bf16x8 a[4], bg[2], bu[2];
            #pragma unroll
            for (int i = 0; i < 4; i++)
                a[i] = *(const bf16x8*)&sA[cur][wm * 64 + i * 16 + l15][rg];
            #pragma unroll
            for (int j = 0; j < 2; j++) {
                bg[j] = *(const bf16x8*)&sB[cur][wn * 32 + j * 16 + l15][rg];
                bu[j] = *(const bf16x8*)&sB[cur][128 + wn * 32 + j * 16 + l15][rg];
            }
            #pragma unroll
            for (int i = 0; i < 4; i++)
                #pragma unroll
                for (int j = 0; j < 2; j++) {
                    acc[i][j]     = __builtin_amdgcn_mfma_f32_16x16x32_bf16(a[i], bg[j], acc[i][j], 0, 0, 0);
                    acc[i][2 + j] = __builtin_amdgcn_mfma_f32_16x16x32_bf16(a[i], bu[j], acc[i][2 + j], 0, 0, 0);
                }
            __builtin_amdgcn_sched_barrier(0);  // keep MFMAs before barrier
            __builtin_amdgcn_s_barrier();       // cur reusable for next stage
        }

        // epilogue: act = silu(gate) * up
        #pragma unroll
        for (int i = 0; i < 4; i++) {
            #pragma unroll
            for (int rr = 0; rr < 4; rr++) {
                int m = m0 + wm * 64 + i * 16 + lg * 4 + rr;
                if (m < mend) {
                    #pragma unroll
                    for (int j = 0; j < 2; j++) {
                        float gv = acc[i][j][rr];
                        float uv = acc[i][2 + j][rr];
                        float sv = gv / (1.f + __expf(-gv));
                        act[(size_t)m * I_DIM + c0 + wn * 32 + j * 16 + l15] = (bf16_t)(sv * uv);
                    }
                }
            }
        }
    }
}

// ---------------------------------------------------------------- GEMM2 (+ scale, k-split x4)
// R8 engine; kz = 4 K-slices of 512 -> nit = n_slots*16 (~528).
__global__ __launch_bounds__(512)
void gemm2_kernel(const bf16_t* __restrict__ act,
                  const bf16_t* __restrict__ w2bf,
                  const int* __restrict__ offsets,
                  const int* __restrict__ tile_e,
                  const int* __restrict__ tile_m0,
                  const int* __restrict__ n_slots,
                  const int* __restrict__ pair_dst,
                  const float* __restrict__ pair_wt,
                  bf16_t* __restrict__ ybuf) {
    __shared__ __align__(16) bf16_t sA[2][128][32];
    __shared__ __align__(16) bf16_t sB[2][256][32];

    int tid = threadIdx.x;
    int lane = tid & 63, w = tid >> 6;
    int wm = w >> 2, wn = w & 3;
    int l15 = lane & 15, lg = lane >> 4;
    int sr = lane >> 2, sg = lane & 3;
    int gcol = (sg ^ (sr & 3)) * 8;
    int rg   = (lg ^ (l15 & 3)) * 8;

    int nit = *n_slots * 16;   // 4 n0-groups x 4 kz
    for (int it = blockIdx.x; it < nit; it += gridDim.x) {
        int slot = it >> 4;
        int n0   = ((it >> 2) & 3) << 8;   // out cols [n0, n0+256)
        int kz   = it & 3;
        int kb   = kz << 9;                // k-slice base (512)
        int e    = tile_e[slot];
        int m0   = tile_m0[slot];
        int mend = offsets[e + 1];
        const bf16_t* w2e = w2bf + (size_t)e * H_DIM * I_DIM;

        // rows >= mend read neighbor arena data (masked at epilogue)
        const bf16_t* gA0 = act + (size_t)(m0 + w * 16 + sr) * I_DIM + kb + gcol;
        const bf16_t* gB0 = w2e + (size_t)(n0 + w * 32 + sr) * I_DIM + kb + gcol;
        const bf16_t* gB1 = w2e + (size_t)(n0 + w * 32 + 16 + sr) * I_DIM + kb + gcol;

        f32x4 acc[4][4];
        #pragma unroll
        for (int i = 0; i < 4; i++)
            #pragma unroll
            for (int j = 0; j < 4; j++) acc[i][j] = zero4();

        GLOAD_LDS16(gA0, &sA[0][w * 16][0]);
        GLOAD_LDS16(gB0, &sB[0][w * 32][0]);
        GLOAD_LDS16(gB1, &sB[0][w * 32 + 16][0]);

        for (int t = 0; t < 16; t++) {     // K-slice 512 = 16 steps
            int cur = t & 1;
            if (t < 15) {
                int k0 = (t + 1) * 32;
                GLOAD_LDS16(gA0 + k0, &sA[cur ^ 1][w * 16][0]);
                GLOAD_LDS16(gB0 + k0, &sB[cur ^ 1][w * 32][0]);
                GLOAD_LDS16(gB1 + k0, &sB[cur ^ 1][w * 32 + 16][0]);
                asm volatile("s_waitcnt vmcnt(3)" ::: "memory");
            } else {
                asm volatile("s_waitcnt vmcnt(0)" ::: "memory");
            }
            __builtin_amdgcn_s_barrier();

            bf16x8 a[4], b[4];
            #pragma unroll
            for (int i = 0; i < 4; i++)
                a[i] = *(const bf16x8*)&sA[cur][wm * 64 + i * 16 + l15][rg];
            #pragma unroll
            for (int j = 0; j < 4; j++)
                b[j] = *(const bf16x8*)&sB[cur][wn * 64 + j * 16 + l15][rg];
            #pragma unroll
            for (int i = 0; i < 4; i++)
                #pragma unroll
                for (int j = 0; j < 4; j++)
                    acc[i][j] = __builtin_amdgcn_mfma_f32_16x16x32_bf16(a[i], b[j], acc[i][j], 0, 0, 0);
            __builtin_amdgcn_sched_barrier(0);
            __builtin_amdgcn_s_barrier();
        }

        bf16_t* ybufz = ybuf + (size_t)kz * P_MAX * H_DIM;
        #pragma unroll
        for (int i = 0; i < 4; i++) {
            #pragma unroll
            for (int rr = 0; rr < 4; rr++) {
                int m = m0 + wm * 64 + i * 16 + lg * 4 + rr;
                if (m < mend) {
                    int   dst = pair_dst[m];
                    float wv  = pair_wt[m];
                    #pragma unroll
                    for (int j = 0; j < 4; j++)
                        ybufz[(size_t)dst * H_DIM + n0 + wn * 64 + j * 16 + l15] =
                            (bf16_t)(acc[i][j][rr] * wv);
                }
            }
        }
    }
}

// ---------------------------------------------------------------- combine
// ybuf bf16, 4 kz-slices x 2 pairs: sum 8 bf16x8 in f32, write 8 f32.
__global__ void combine_kernel(const bf16_t* __restrict__ ybuf,
                               float* __restrict__ out) {
    int idx = blockIdx.x * 256 + threadIdx.x;   // one 8-elem chunk each
    int t = idx >> 7;                           // 128 chunks per token row
    int h = (idx & 127) * 8;
    const size_t SL = (size_t)P_MAX * H_DIM;
    float s[8];
    #pragma unroll
    for (int j = 0; j < 8; j++) s[j] = 0.f;
    #pragma unroll
    for (int kz = 0; kz < 4; kz++) {
        bf16x8 y0 = *(const bf16x8*)(ybuf + kz * SL + (size_t)(t * 2)     * H_DIM + h);
        bf16x8 y1 = *(const bf16x8*)(ybuf + kz * SL + (size_t)(t * 2 + 1) * H_DIM + h);
        #pragma unroll
        for (int j = 0; j < 8; j++) s[j] += (float)y0[j] + (float)y1[j];
    }
    f32x4 o0, o1;
    #pragma unroll
    for (int j = 0; j < 4; j++) { o0[j] = s[j]; o1[j] = s[4 + j]; }
    *(f32x4*)(out + (size_t)t * H_DIM + h)     = o0;
    *(f32x4*)(out + (size_t)t * H_DIM + h + 4) = o1;
}

// ---------------------------------------------------------------- launch
extern "C" void kernel_launch(void* const* d_in, const int* in_sizes, int n_in,
                              void* d_out, int out_size, void* d_ws, size_t ws_size,
                              hipStream_t stream) {
    const float* hidden = (const float*)d_in[0];
    const float* w1     = (const float*)d_in[1];
    const float* w2     = (const float*)d_in[2];
    const float* gating = (const float*)d_in[3];
    float* out = (float*)d_out;

    const size_t N0 = (size_t)T_TOK * H_DIM;             // hidden elems
    const size_t N1 = (size_t)E_NUM * 2 * I_DIM * H_DIM; // w1 elems
    const size_t N2 = (size_t)E_NUM * H_DIM * I_DIM;     // w2 elems

    char* ws = (char*)d_ws;
    size_t off = 0;
    auto alloc = [&](size_t bytes) -> void* {
        void* p = ws + off;
        off += (bytes + 255) & ~(size_t)255;
        return p;
    };
    // order matters: act must not be last (gemm2 A-staging over-reads <=260KB)
    bf16_t* ybuf  = (bf16_t*)alloc((size_t)4 * P_MAX * H_DIM * sizeof(bf16_t));   // 33.6 MB (4 slices)
    bf16_t* act   = (bf16_t*)alloc((size_t)P_MAX * I_DIM * sizeof(bf16_t));       // 16.8 MB
    bf16_t* hbf   = (bf16_t*)alloc(N0 * sizeof(bf16_t));                          //  4.2 MB
    bf16_t* w1bf  = (bf16_t*)alloc(N1 * sizeof(bf16_t));                          // 67.1 MB
    bf16_t* w2bf  = (bf16_t*)alloc(N2 * sizeof(bf16_t));                          // 33.6 MB
    int*    expert_id  = (int*)alloc(P_MAX * sizeof(int));
    float*  wt         = (float*)alloc(P_MAX * sizeof(float));
    int*    pair_token = (int*)alloc(P_MAX * sizeof(int));
    int*    pair_dst   = (int*)alloc(P_MAX * sizeof(int));
    float*  pair_wt    = (float*)alloc(P_MAX * sizeof(float));
    int*    counts     = (int*)alloc(E_NUM * sizeof(int));
    int*    offsets    = (int*)alloc((E_NUM + 1) * sizeof(int));
    int*    cursor     = (int*)alloc(E_NUM * sizeof(int));
    int*    n_slots    = (int*)alloc(sizeof(int));
    int*    tile_e     = (int*)alloc(MAX_SLOTS * sizeof(int));
    int*    tile_m0    = (int*)alloc(MAX_SLOTS * sizeof(int));

    init_kernel<<<1, 64, 0, stream>>>(counts, cursor);
    router_kernel<<<(T_TOK + 255) / 256, 256, 0, stream>>>(gating, expert_id, wt, counts);
    scan_kernel<<<1, 1, 0, stream>>>(counts, offsets, tile_e, tile_m0, n_slots);
    scatter_kernel<<<(T_TOK + 255) / 256, 256, 0, stream>>>(expert_id, wt, offsets, cursor,
                                                            pair_token, pair_dst, pair_wt);
    convert_hw1_kernel<<<(int)((N0 + N1) / (256 * 16)), 256, 0, stream>>>(hidden, w1, hbf, w1bf);
    gemm1_kernel<<<CONV_BLKS + 768, 512, 0, stream>>>(
        hbf, w1bf, w2, w2bf, pair_token, offsets, tile_e, tile_m0, n_slots, act);
    gemm2_kernel<<<768, 512, 0, stream>>>(
        act, w2bf, offsets, tile_e, tile_m0, n_slots, pair_dst, pair_wt, ybuf);
    combine_kernel<<<(T_TOK * H_DIM / 8) / 256, 256, 0, stream>>>(ybuf, out);

    (void)in_sizes; (void)n_in; (void)out_size; (void)ws_size;
}

// Round 21
// 194.785 us; speedup vs baseline: 1.0622x; 1.0622x over previous
//
#include <hip/hip_runtime.h>
#include <hip/hip_bf16.h>
#include <math.h>

// Problem constants (fixed by the reference file)
#define T_TOK 2048
#define H_DIM 1024
#define I_DIM 2048
#define E_NUM 8
#define TOPK  2
#define P_MAX (T_TOK * TOPK)   // 4096 (token, k) pairs
#define MAX_SLOTS 40           // max 128-row slots: 4096/128 + 8
#define CONV_BLKS 128          // gemm1-fused w2-convert blocks

typedef __bf16 bf16_t;
typedef __attribute__((ext_vector_type(8))) __bf16 bf16x8;
typedef __attribute__((ext_vector_type(4))) float  f32x4;

// global_load_lds: per-lane GLOBAL address, wave-uniform LDS base; lane n
// writes lds_base + n*16 bytes (m104/m108).
#define GLOAD_LDS16(gptr, lptr)                                                   \
    __builtin_amdgcn_global_load_lds(                                             \
        (const __attribute__((address_space(1))) void*)(gptr),                    \
        (__attribute__((address_space(3))) void*)(lptr), 16, 0, 0)

__device__ inline f32x4 zero4() {
    f32x4 z; z[0] = 0.f; z[1] = 0.f; z[2] = 0.f; z[3] = 0.f; return z;
}

__device__ inline bf16x8 cvt8(f32x4 a, f32x4 b) {
    bf16x8 o;
    o[0] = (bf16_t)a[0]; o[1] = (bf16_t)a[1]; o[2] = (bf16_t)a[2]; o[3] = (bf16_t)a[3];
    o[4] = (bf16_t)b[0]; o[5] = (bf16_t)b[1]; o[6] = (bf16_t)b[2]; o[7] = (bf16_t)b[3];
    return o;
}

// ---------------------------------------------------------------- init
__global__ void init_kernel(int* counts, int* cursor) {
    int i = threadIdx.x;
    if (i < E_NUM) { counts[i] = 0; cursor[i] = 0; }
}

// ---------------------------------------------------------------- router
__global__ void router_kernel(const float* __restrict__ gating,
                              int* __restrict__ expert_id,
                              float* __restrict__ wt,
                              int* __restrict__ counts) {
    int t = blockIdx.x * blockDim.x + threadIdx.x;
    if (t >= T_TOK) return;
    float l[E_NUM];
    float m = -1e30f;
    #pragma unroll
    for (int e = 0; e < E_NUM; e++) { l[e] = gating[t * E_NUM + e]; m = fmaxf(m, l[e]); }
    float p[E_NUM];
    #pragma unroll
    for (int e = 0; e < E_NUM; e++) p[e] = __expf(l[e] - m);
    int i0 = 0; float p0 = p[0];
    #pragma unroll
    for (int e = 1; e < E_NUM; e++) if (p[e] > p0) { p0 = p[e]; i0 = e; }
    int i1 = -1; float p1 = -1.f;
    #pragma unroll
    for (int e = 0; e < E_NUM; e++) if (e != i0 && p[e] > p1) { p1 = p[e]; i1 = e; }
    float inv = 1.f / (p0 + p1);
    expert_id[t * 2 + 0] = i0; wt[t * 2 + 0] = p0 * inv;
    expert_id[t * 2 + 1] = i1; wt[t * 2 + 1] = p1 * inv;
    atomicAdd(&counts[i0], 1);
    atomicAdd(&counts[i1], 1);
}

// ---------------------------------------------------------------- scan + tile map
__global__ void scan_kernel(const int* __restrict__ counts,
                            int* __restrict__ offsets,
                            int* __restrict__ tile_e, int* __restrict__ tile_m0,
                            int* __restrict__ n_slots) {
    if (threadIdx.x != 0 || blockIdx.x != 0) return;
    int off = 0;
    for (int e = 0; e < E_NUM; e++) { offsets[e] = off; off += counts[e]; }
    offsets[E_NUM] = off;
    int s = 0;
    for (int e = 0; e < E_NUM; e++)
        for (int m0 = offsets[e]; m0 < offsets[e + 1]; m0 += 128) {
            tile_e[s] = e; tile_m0[s] = m0; s++;
        }
    *n_slots = s;
}

// ---------------------------------------------------------------- scatter
__global__ void scatter_kernel(const int* __restrict__ expert_id,
                               const float* __restrict__ wt,
                               const int* __restrict__ offsets,
                               int* __restrict__ cursor,
                               int* __restrict__ pair_token,
                               int* __restrict__ pair_dst,
                               float* __restrict__ pair_wt) {
    int t = blockIdx.x * blockDim.x + threadIdx.x;
    if (t >= T_TOK) return;
    #pragma unroll
    for (int k = 0; k < TOPK; k++) {
        int e = expert_id[t * 2 + k];
        int p = offsets[e] + atomicAdd(&cursor[e], 1);
        pair_token[p] = t;
        pair_dst[p]   = t * 2 + k;
        pair_wt[p]    = wt[t * 2 + k];
    }
}

// ---------------------------------------------------------------- f32 -> bf16 convert
// One launch for hidden + w1 (concatenated flat index; N0 is 16-divisible).
__global__ void convert_hw1_kernel(const float* __restrict__ hidden,
                                   const float* __restrict__ w1,
                                   bf16_t* __restrict__ hbf,
                                   bf16_t* __restrict__ w1bf) {
    const size_t N0 = (size_t)T_TOK * H_DIM;
    size_t g = (size_t)blockIdx.x * blockDim.x + threadIdx.x;
    size_t i = g * 16;
    const float* src; bf16_t* dst; size_t o;
    if (i < N0) { src = hidden; dst = hbf;  o = i; }
    else        { src = w1;     dst = w1bf; o = i - N0; }
    f32x4 v0 = *(const f32x4*)(src + o);
    f32x4 v1 = *(const f32x4*)(src + o + 4);
    f32x4 v2 = *(const f32x4*)(src + o + 8);
    f32x4 v3 = *(const f32x4*)(src + o + 12);
    *(bf16x8*)(dst + o)     = cvt8(v0, v1);
    *(bf16x8*)(dst + o + 8) = cvt8(v2, v3);
}

// ---------------------------------------------------------------- GEMM1 + SwiGLU (+ fused w2 convert)
// R8/R13 counted-vmcnt engine. Blocks [0, CONV_BLKS) convert w2 f32->bf16
// (grid-stride) and exit — gemm1 is HBM-light, so this streams under it;
// kernel boundary orders w2bf before gemm2. Blocks >= CONV_BLKS run gemm1
// items persistently. (512,4): best measured; (512,6) spills (R12), (512)
// alone regressed (R20).
__global__ __launch_bounds__(512, 4)
void gemm1_kernel(const bf16_t* __restrict__ hbf,
                  const bf16_t* __restrict__ w1bf,
                  const float* __restrict__ w2,
                  bf16_t* __restrict__ w2bf,
                  const int* __restrict__ pair_token,
                  const int* __restrict__ offsets,
                  const int* __restrict__ tile_e,
                  const int* __restrict__ tile_m0,
                  const int* __restrict__ n_slots,
                  bf16_t* __restrict__ act) {
    __shared__ __align__(16) bf16_t sA[2][128][32];  // 16 KB
    __shared__ __align__(16) bf16_t sB[2][256][32];  // 32 KB

    int tid = threadIdx.x;

    if (blockIdx.x < CONV_BLKS) {   // ---- w2 convert role
        const size_t N2c = (size_t)E_NUM * H_DIM * I_DIM / 16;  // 16-elem chunks
        size_t stride = (size_t)CONV_BLKS * 512;
        for (size_t g = (size_t)blockIdx.x * 512 + tid; g < N2c; g += stride) {
            size_t i = g * 16;
            f32x4 v0 = *(const f32x4*)(w2 + i);
            f32x4 v1 = *(const f32x4*)(w2 + i + 4);
            f32x4 v2 = *(const f32x4*)(w2 + i + 8);
            f32x4 v3 = *(const f32x4*)(w2 + i + 12);
            *(bf16x8*)(w2bf + i)     = cvt8(v0, v1);
            *(bf16x8*)(w2bf + i + 8) = cvt8(v2, v3);
        }
        return;
    }

    int lane = tid & 63, w = tid >> 6;     // 8 waves
    int wm = w >> 2, wn = w & 3;           // 2M x 4N
    int l15 = lane & 15, lg = lane >> 4;
    int sr = lane >> 2, sg = lane & 3;     // staging sub-row / granule
    int gcol = (sg ^ (sr & 3)) * 8;        // inverse-swizzled SOURCE granule
    int rg   = (lg ^ (l15 & 3)) * 8;       // swizzled READ granule

    int nit = *n_slots * 16;
    for (int it = blockIdx.x - CONV_BLKS; it < nit; it += gridDim.x - CONV_BLKS) {
        int slot = it >> 4;
        int c0   = (it & 15) << 7;         // act cols [c0, c0+128)
        int e    = tile_e[slot];
        int m0   = tile_m0[slot];
        int mend = offsets[e + 1];
        const bf16_t* w1e = w1bf + (size_t)e * (2 * I_DIM) * H_DIM;

        // staging addresses (k0 added in loop)
        int parow = m0 + w * 16 + sr;
        int tok = (parow < mend) ? pair_token[parow] : 0;  // dummy, masked later
        const bf16_t* gA0 = hbf + (size_t)tok * H_DIM + gcol;
        int br0 = w * 32 + sr, br1 = br0 + 16;
        int wr0 = (br0 < 128) ? (c0 + br0) : (I_DIM + c0 + br0 - 128);
        int wr1 = (br1 < 128) ? (c0 + br1) : (I_DIM + c0 + br1 - 128);
        const bf16_t* gB0 = w1e + (size_t)wr0 * H_DIM + gcol;
        const bf16_t* gB1 = w1e + (size_t)wr1 * H_DIM + gcol;

        f32x4 acc[4][4];  // j=0,1 gate; j=2,3 up
        #pragma unroll
        for (int i = 0; i < 4; i++)
            #pragma unroll
            for (int j = 0; j < 4; j++) acc[i][j] = zero4();

        // prologue: stage K-step 0 into buf 0
        GLOAD_LDS16(gA0, &sA[0][w * 16][0]);
        GLOAD_LDS16(gB0, &sB[0][w * 32][0]);
        GLOAD_LDS16(gB1, &sB[0][w * 32 + 16][0]);

        for (int t = 0; t < 32; t++) {
            int cur = t & 1;
            if (t < 31) {
                int k0 = (t + 1) * 32;
                GLOAD_LDS16(gA0 + k0, &sA[cur ^ 1][w * 16][0]);
                GLOAD_LDS16(gB0 + k0, &sB[cur ^ 1][w * 32][0]);
                GLOAD_LDS16(gB1 + k0, &sB[cur ^ 1][w * 32 + 16][0]);
                asm volatile("s_waitcnt vmcnt(3)" ::: "memory");
            } else {
                asm volatile("s_waitcnt vmcnt(0)" ::: "memory");
            }
            __builtin_amdgcn_s_barrier();   // all waves' cur-tile loads landed

            bf16x8 a[4], bg[2], bu[2];
            #pragma unroll
            for (int i = 0; i < 4; i++)
                a[i] = *(const bf16x8*)&sA[cur][wm * 64 + i * 16 + l15][rg];
            #pragma unroll
            for (int j = 0; j < 2; j++) {
                bg[j] = *(const bf16x8*)&sB[cur][wn * 32 + j * 16 + l15][rg];
                bu[j] = *(const bf16x8*)&sB[cur][128 + wn * 32 + j * 16 + l15][rg];
            }
            #pragma unroll
            for (int i = 0; i < 4; i++)
                #pragma unroll
                for (int j = 0; j < 2; j++) {
                    acc[i][j]     = __builtin_amdgcn_mfma_f32_16x16x32_bf16(a[i], bg[j], acc[i][j], 0, 0, 0);
                    acc[i][2 + j] = __builtin_amdgcn_mfma_f32_16x16x32_bf16(a[i], bu[j], acc[i][2 + j], 0, 0, 0);
                }
            __builtin_amdgcn_sched_barrier(0);  // keep MFMAs before barrier
            __builtin_amdgcn_s_barrier();       // cur reusable for next stage
        }

        // epilogue: act = silu(gate) * up
        #pragma unroll
        for (int i = 0; i < 4; i++) {
            #pragma unroll
            for (int rr = 0; rr < 4; rr++) {
                int m = m0 + wm * 64 + i * 16 + lg * 4 + rr;
                if (m < mend) {
                    #pragma unroll
                    for (int j = 0; j < 2; j++) {
                        float gv = acc[i][j][rr];
                        float uv = acc[i][2 + j][rr];
                        float sv = gv / (1.f + __expf(-gv));
                        act[(size_t)m * I_DIM + c0 + wn * 32 + j * 16 + l15] = (bf16_t)(sv * uv);
                    }
                }
            }
        }
    }
}

// ---------------------------------------------------------------- GEMM2 (+ scale, k-split x4)
// R8 engine; kz = 4 K-slices of 512 -> nit = n_slots*16 (~528) fills the
// resident-block slots.
__global__ __launch_bounds__(512, 4)
void gemm2_kernel(const bf16_t* __restrict__ act,
                  const bf16_t* __restrict__ w2bf,
                  const int* __restrict__ offsets,
                  const int* __restrict__ tile_e,
                  const int* __restrict__ tile_m0,
                  const int* __restrict__ n_slots,
                  const int* __restrict__ pair_dst,
                  const float* __restrict__ pair_wt,
                  bf16_t* __restrict__ ybuf) {
    __shared__ __align__(16) bf16_t sA[2][128][32];
    __shared__ __align__(16) bf16_t sB[2][256][32];

    int tid = threadIdx.x;
    int lane = tid & 63, w = tid >> 6;
    int wm = w >> 2, wn = w & 3;
    int l15 = lane & 15, lg = lane >> 4;
    int sr = lane >> 2, sg = lane & 3;
    int gcol = (sg ^ (sr & 3)) * 8;
    int rg   = (lg ^ (l15 & 3)) * 8;

    int nit = *n_slots * 16;   // 4 n0-groups x 4 kz
    for (int it = blockIdx.x; it < nit; it += gridDim.x) {
        int slot = it >> 4;
        int n0   = ((it >> 2) & 3) << 8;   // out cols [n0, n0+256)
        int kz   = it & 3;
        int kb   = kz << 9;                // k-slice base (512)
        int e    = tile_e[slot];
        int m0   = tile_m0[slot];
        int mend = offsets[e + 1];
        const bf16_t* w2e = w2bf + (size_t)e * H_DIM * I_DIM;

        // rows >= mend read neighbor arena data (masked at epilogue)
        const bf16_t* gA0 = act + (size_t)(m0 + w * 16 + sr) * I_DIM + kb + gcol;
        const bf16_t* gB0 = w2e + (size_t)(n0 + w * 32 + sr) * I_DIM + kb + gcol;
        const bf16_t* gB1 = w2e + (size_t)(n0 + w * 32 + 16 + sr) * I_DIM + kb + gcol;

        f32x4 acc[4][4];
        #pragma unroll
        for (int i = 0; i < 4; i++)
            #pragma unroll
            for (int j = 0; j < 4; j++) acc[i][j] = zero4();

        GLOAD_LDS16(gA0, &sA[0][w * 16][0]);
        GLOAD_LDS16(gB0, &sB[0][w * 32][0]);
        GLOAD_LDS16(gB1, &sB[0][w * 32 + 16][0]);

        for (int t = 0; t < 16; t++) {     // K-slice 512 = 16 steps
            int cur = t & 1;
            if (t < 15) {
                int k0 = (t + 1) * 32;
                GLOAD_LDS16(gA0 + k0, &sA[cur ^ 1][w * 16][0]);
                GLOAD_LDS16(gB0 + k0, &sB[cur ^ 1][w * 32][0]);
                GLOAD_LDS16(gB1 + k0, &sB[cur ^ 1][w * 32 + 16][0]);
                asm volatile("s_waitcnt vmcnt(3)" ::: "memory");
            } else {
                asm volatile("s_waitcnt vmcnt(0)" ::: "memory");
            }
            __builtin_amdgcn_s_barrier();

            bf16x8 a[4], b[4];
            #pragma unroll
            for (int i = 0; i < 4; i++)
                a[i] = *(const bf16x8*)&sA[cur][wm * 64 + i * 16 + l15][rg];
            #pragma unroll
            for (int j = 0; j < 4; j++)
                b[j] = *(const bf16x8*)&sB[cur][wn * 64 + j * 16 + l15][rg];
            #pragma unroll
            for (int i = 0; i < 4; i++)
                #pragma unroll
                for (int j = 0; j < 4; j++)
                    acc[i][j] = __builtin_amdgcn_mfma_f32_16x16x32_bf16(a[i], b[j], acc[i][j], 0, 0, 0);
            __builtin_amdgcn_sched_barrier(0);
            __builtin_amdgcn_s_barrier();
        }

        bf16_t* ybufz = ybuf + (size_t)kz * P_MAX * H_DIM;
        #pragma unroll
        for (int i = 0; i < 4; i++) {
            #pragma unroll
            for (int rr = 0; rr < 4; rr++) {
                int m = m0 + wm * 64 + i * 16 + lg * 4 + rr;
                if (m < mend) {
                    int   dst = pair_dst[m];
                    float wv  = pair_wt[m];
                    #pragma unroll
                    for (int j = 0; j < 4; j++)
                        ybufz[(size_t)dst * H_DIM + n0 + wn * 64 + j * 16 + l15] =
                            (bf16_t)(acc[i][j][rr] * wv);
                }
            }
        }
    }
}

// ---------------------------------------------------------------- combine
// ybuf bf16, 4 kz-slices x 2 pairs: sum 8 bf16x8 in f32, write 8 f32.
__global__ void combine_kernel(const bf16_t* __restrict__ ybuf,
                               float* __restrict__ out) {
    int idx = blockIdx.x * 256 + threadIdx.x;   // one 8-elem chunk each
    int t = idx >> 7;                           // 128 chunks per token row
    int h = (idx & 127) * 8;
    const size_t SL = (size_t)P_MAX * H_DIM;
    float s[8];
    #pragma unroll
    for (int j = 0; j < 8; j++) s[j] = 0.f;
    #pragma unroll
    for (int kz = 0; kz < 4; kz++) {
        bf16x8 y0 = *(const bf16x8*)(ybuf + kz * SL + (size_t)(t * 2)     * H_DIM + h);
        bf16x8 y1 = *(const bf16x8*)(ybuf + kz * SL + (size_t)(t * 2 + 1) * H_DIM + h);
        #pragma unroll
        for (int j = 0; j < 8; j++) s[j] += (float)y0[j] + (float)y1[j];
    }
    f32x4 o0, o1;
    #pragma unroll
    for (int j = 0; j < 4; j++) { o0[j] = s[j]; o1[j] = s[4 + j]; }
    *(f32x4*)(out + (size_t)t * H_DIM + h)     = o0;
    *(f32x4*)(out + (size_t)t * H_DIM + h + 4) = o1;
}

// ---------------------------------------------------------------- launch
extern "C" void kernel_launch(void* const* d_in, const int* in_sizes, int n_in,
                              void* d_out, int out_size, void* d_ws, size_t ws_size,
                              hipStream_t stream) {
    const float* hidden = (const float*)d_in[0];
    const float* w1     = (const float*)d_in[1];
    const float* w2     = (const float*)d_in[2];
    const float* gating = (const float*)d_in[3];
    float* out = (float*)d_out;

    const size_t N0 = (size_t)T_TOK * H_DIM;             // hidden elems
    const size_t N1 = (size_t)E_NUM * 2 * I_DIM * H_DIM; // w1 elems
    const size_t N2 = (size_t)E_NUM * H_DIM * I_DIM;     // w2 elems

    char* ws = (char*)d_ws;
    size_t off = 0;
    auto alloc = [&](size_t bytes) -> void* {
        void* p = ws + off;
        off += (bytes + 255) & ~(size_t)255;
        return p;
    };
    // order matters: act must not be last (gemm2 A-staging over-reads <=260KB)
    bf16_t* ybuf  = (bf16_t*)alloc((size_t)4 * P_MAX * H_DIM * sizeof(bf16_t));   // 33.6 MB (4 slices)
    bf16_t* act   = (bf16_t*)alloc((size_t)P_MAX * I_DIM * sizeof(bf16_t));       // 16.8 MB
    bf16_t* hbf   = (bf16_t*)alloc(N0 * sizeof(bf16_t));                          //  4.2 MB
    bf16_t* w1bf  = (bf16_t*)alloc(N1 * sizeof(bf16_t));                          // 67.1 MB
    bf16_t* w2bf  = (bf16_t*)alloc(N2 * sizeof(bf16_t));                          // 33.6 MB
    int*    expert_id  = (int*)alloc(P_MAX * sizeof(int));
    float*  wt         = (float*)alloc(P_MAX * sizeof(float));
    int*    pair_token = (int*)alloc(P_MAX * sizeof(int));
    int*    pair_dst   = (int*)alloc(P_MAX * sizeof(int));
    float*  pair_wt    = (float*)alloc(P_MAX * sizeof(float));
    int*    counts     = (int*)alloc(E_NUM * sizeof(int));
    int*    offsets    = (int*)alloc((E_NUM + 1) * sizeof(int));
    int*    cursor     = (int*)alloc(E_NUM * sizeof(int));
    int*    n_slots    = (int*)alloc(sizeof(int));
    int*    tile_e     = (int*)alloc(MAX_SLOTS * sizeof(int));
    int*    tile_m0    = (int*)alloc(MAX_SLOTS * sizeof(int));

    init_kernel<<<1, 64, 0, stream>>>(counts, cursor);
    router_kernel<<<(T_TOK + 255) / 256, 256, 0, stream>>>(gating, expert_id, wt, counts);
    scan_kernel<<<1, 1, 0, stream>>>(counts, offsets, tile_e, tile_m0, n_slots);
    scatter_kernel<<<(T_TOK + 255) / 256, 256, 0, stream>>>(expert_id, wt, offsets, cursor,
                                                            pair_token, pair_dst, pair_wt);
    convert_hw1_kernel<<<(int)((N0 + N1) / (256 * 16)), 256, 0, stream>>>(hidden, w1, hbf, w1bf);
    gemm1_kernel<<<CONV_BLKS + 768, 512, 0, stream>>>(
        hbf, w1bf, w2, w2bf, pair_token, offsets, tile_e, tile_m0, n_slots, act);
    gemm2_kernel<<<768, 512, 0, stream>>>(
        act, w2bf, offsets, tile_e, tile_m0, n_slots, pair_dst, pair_wt, ybuf);
    combine_kernel<<<(T_TOK * H_DIM / 8) / 256, 256, 0, stream>>>(ybuf, out);

    (void)in_sizes; (void)n_in; (void)out_size; (void)ws_size;
}

// Round 22
// 155.245 us; speedup vs baseline: 1.3327x; 1.2547x over previous
//
#include <hip/hip_runtime.h>
#include <hip/hip_bf16.h>
#include <math.h>

// Problem constants (fixed by the reference file)
#define T_TOK 2048
#define H_DIM 1024
#define I_DIM 2048
#define E_NUM 8
#define TOPK  2
#define P_MAX (T_TOK * TOPK)   // 4096 (token, k) pairs
#define MAX_SLOTS 40           // max 128-row slots: 4096/128 + 8
#define CONV_BLKS 128          // gemm1-fused w2-convert blocks

typedef __bf16 bf16_t;
typedef __attribute__((ext_vector_type(8))) __bf16 bf16x8;
typedef __attribute__((ext_vector_type(4))) float  f32x4;

// global_load_lds: per-lane GLOBAL address, wave-uniform LDS base; lane n
// writes lds_base + n*16 bytes (m104/m108).
#define GLOAD_LDS16(gptr, lptr)                                                   \
    __builtin_amdgcn_global_load_lds(                                             \
        (const __attribute__((address_space(1))) void*)(gptr),                    \
        (__attribute__((address_space(3))) void*)(lptr), 16, 0, 0)

__device__ inline f32x4 zero4() {
    f32x4 z; z[0] = 0.f; z[1] = 0.f; z[2] = 0.f; z[3] = 0.f; return z;
}

__device__ inline bf16x8 cvt8(f32x4 a, f32x4 b) {
    bf16x8 o;
    o[0] = (bf16_t)a[0]; o[1] = (bf16_t)a[1]; o[2] = (bf16_t)a[2]; o[3] = (bf16_t)a[3];
    o[4] = (bf16_t)b[0]; o[5] = (bf16_t)b[1]; o[6] = (bf16_t)b[2]; o[7] = (bf16_t)b[3];
    return o;
}

// ---------------------------------------------------------------- convert + fused routing
// Block 0: full routing chain (router -> scan -> scatter) with
// __syncthreads phase ordering; 256 thr x 8 tokens each, top-2 state held
// in registers between phases, counts/cursor in LDS. Blocks >= 1: f32->bf16
// convert of hidden + w1 (one 16-elem chunk per thread).
__global__ __launch_bounds__(256)
void convert_route_kernel(const float* __restrict__ hidden,
                          const float* __restrict__ w1,
                          const float* __restrict__ gating,
                          bf16_t* __restrict__ hbf,
                          bf16_t* __restrict__ w1bf,
                          int* __restrict__ offsets,      // [E_NUM+1]
                          int* __restrict__ tile_e,
                          int* __restrict__ tile_m0,
                          int* __restrict__ n_slots,
                          int* __restrict__ pair_token,
                          int* __restrict__ pair_dst,
                          float* __restrict__ pair_wt) {
    const size_t N0 = (size_t)T_TOK * H_DIM;
    int tid = threadIdx.x;

    if (blockIdx.x == 0) {   // ---- routing role
        __shared__ int cnt[E_NUM];
        __shared__ int cur[E_NUM];
        __shared__ int offs[E_NUM + 1];
        if (tid < E_NUM) { cnt[tid] = 0; cur[tid] = 0; }
        __syncthreads();

        int   id0[8], id1[8];
        float wt0[8], wt1[8];
        #pragma unroll
        for (int q = 0; q < 8; q++) {
            int t = tid * 8 + q;
            float l[E_NUM];
            float m = -1e30f;
            #pragma unroll
            for (int e = 0; e < E_NUM; e++) { l[e] = gating[t * E_NUM + e]; m = fmaxf(m, l[e]); }
            float p[E_NUM];
            #pragma unroll
            for (int e = 0; e < E_NUM; e++) p[e] = __expf(l[e] - m);
            int i0 = 0; float p0 = p[0];
            #pragma unroll
            for (int e = 1; e < E_NUM; e++) if (p[e] > p0) { p0 = p[e]; i0 = e; }
            int i1 = -1; float p1 = -1.f;
            #pragma unroll
            for (int e = 0; e < E_NUM; e++) if (e != i0 && p[e] > p1) { p1 = p[e]; i1 = e; }
            float inv = 1.f / (p0 + p1);
            id0[q] = i0; wt0[q] = p0 * inv;
            id1[q] = i1; wt1[q] = p1 * inv;
            atomicAdd(&cnt[i0], 1);
            atomicAdd(&cnt[i1], 1);
        }
        __syncthreads();

        if (tid == 0) {   // scan + tile map
            int off = 0;
            for (int e = 0; e < E_NUM; e++) { offs[e] = off; offsets[e] = off; off += cnt[e]; }
            offs[E_NUM] = off; offsets[E_NUM] = off;
            int s = 0;
            for (int e = 0; e < E_NUM; e++)
                for (int m0 = offs[e]; m0 < offs[e + 1]; m0 += 128) {
                    tile_e[s] = e; tile_m0[s] = m0; s++;
                }
            *n_slots = s;
        }
        __syncthreads();

        #pragma unroll
        for (int q = 0; q < 8; q++) {   // scatter
            int t = tid * 8 + q;
            int p0 = offs[id0[q]] + atomicAdd(&cur[id0[q]], 1);
            pair_token[p0] = t; pair_dst[p0] = t * 2;     pair_wt[p0] = wt0[q];
            int p1 = offs[id1[q]] + atomicAdd(&cur[id1[q]], 1);
            pair_token[p1] = t; pair_dst[p1] = t * 2 + 1; pair_wt[p1] = wt1[q];
        }
        return;
    }

    // ---- convert role (hidden ++ w1, one 16-elem chunk per thread)
    size_t g = (size_t)(blockIdx.x - 1) * 256 + tid;
    size_t i = g * 16;
    const float* src; bf16_t* dst; size_t o;
    if (i < N0) { src = hidden; dst = hbf;  o = i; }
    else        { src = w1;     dst = w1bf; o = i - N0; }
    f32x4 v0 = *(const f32x4*)(src + o);
    f32x4 v1 = *(const f32x4*)(src + o + 4);
    f32x4 v2 = *(const f32x4*)(src + o + 8);
    f32x4 v3 = *(const f32x4*)(src + o + 12);
    *(bf16x8*)(dst + o)     = cvt8(v0, v1);
    *(bf16x8*)(dst + o + 8) = cvt8(v2, v3);
}

// ---------------------------------------------------------------- GEMM1 + SwiGLU (+ fused w2 convert)
// R8/R13 counted-vmcnt engine. Blocks [0, CONV_BLKS) convert w2 f32->bf16
// (grid-stride) and exit — gemm1 is HBM-light, so this streams under it;
// kernel boundary orders w2bf before gemm2. Blocks >= CONV_BLKS run gemm1
// items persistently. (512,4): best measured; (512,6) spills (R12), (512)
// alone regressed (R20).
__global__ __launch_bounds__(512, 4)
void gemm1_kernel(const bf16_t* __restrict__ hbf,
                  const bf16_t* __restrict__ w1bf,
                  const float* __restrict__ w2,
                  bf16_t* __restrict__ w2bf,
                  const int* __restrict__ pair_token,
                  const int* __restrict__ offsets,
                  const int* __restrict__ tile_e,
                  const int* __restrict__ tile_m0,
                  const int* __restrict__ n_slots,
                  bf16_t* __restrict__ act) {
    __shared__ __align__(16) bf16_t sA[2][128][32];  // 16 KB
    __shared__ __align__(16) bf16_t sB[2][256][32];  // 32 KB

    int tid = threadIdx.x;

    if (blockIdx.x < CONV_BLKS) {   // ---- w2 convert role
        const size_t N2c = (size_t)E_NUM * H_DIM * I_DIM / 16;  // 16-elem chunks
        size_t stride = (size_t)CONV_BLKS * 512;
        for (size_t g = (size_t)blockIdx.x * 512 + tid; g < N2c; g += stride) {
            size_t i = g * 16;
            f32x4 v0 = *(const f32x4*)(w2 + i);
            f32x4 v1 = *(const f32x4*)(w2 + i + 4);
            f32x4 v2 = *(const f32x4*)(w2 + i + 8);
            f32x4 v3 = *(const f32x4*)(w2 + i + 12);
            *(bf16x8*)(w2bf + i)     = cvt8(v0, v1);
            *(bf16x8*)(w2bf + i + 8) = cvt8(v2, v3);
        }
        return;
    }

    int lane = tid & 63, w = tid >> 6;     // 8 waves
    int wm = w >> 2, wn = w & 3;           // 2M x 4N
    int l15 = lane & 15, lg = lane >> 4;
    int sr = lane >> 2, sg = lane & 3;     // staging sub-row / granule
    int gcol = (sg ^ (sr & 3)) * 8;        // inverse-swizzled SOURCE granule
    int rg   = (lg ^ (l15 & 3)) * 8;       // swizzled READ granule

    int nit = *n_slots * 16;
    for (int it = blockIdx.x - CONV_BLKS; it < nit; it += gridDim.x - CONV_BLKS) {
        int slot = it >> 4;
        int c0   = (it & 15) << 7;         // act cols [c0, c0+128)
        int e    = tile_e[slot];
        int m0   = tile_m0[slot];
        int mend = offsets[e + 1];
        const bf16_t* w1e = w1bf + (size_t)e * (2 * I_DIM) * H_DIM;

        // staging addresses (k0 added in loop)
        int parow = m0 + w * 16 + sr;
        int tok = (parow < mend) ? pair_token[parow] : 0;  // dummy, masked later
        const bf16_t* gA0 = hbf + (size_t)tok * H_DIM + gcol;
        int br0 = w * 32 + sr, br1 = br0 + 16;
        int wr0 = (br0 < 128) ? (c0 + br0) : (I_DIM + c0 + br0 - 128);
        int wr1 = (br1 < 128) ? (c0 + br1) : (I_DIM + c0 + br1 - 128);
        const bf16_t* gB0 = w1e + (size_t)wr0 * H_DIM + gcol;
        const bf16_t* gB1 = w1e + (size_t)wr1 * H_DIM + gcol;

        f32x4 acc[4][4];  // j=0,1 gate; j=2,3 up
        #pragma unroll
        for (int i = 0; i < 4; i++)
            #pragma unroll
            for (int j = 0; j < 4; j++) acc[i][j] = zero4();

        // prologue: stage K-step 0 into buf 0
        GLOAD_LDS16(gA0, &sA[0][w * 16][0]);
        GLOAD_LDS16(gB0, &sB[0][w * 32][0]);
        GLOAD_LDS16(gB1, &sB[0][w * 32 + 16][0]);

        for (int t = 0; t < 32; t++) {
            int cur = t & 1;
            if (t < 31) {
                int k0 = (t + 1) * 32;
                GLOAD_LDS16(gA0 + k0, &sA[cur ^ 1][w * 16][0]);
                GLOAD_LDS16(gB0 + k0, &sB[cur ^ 1][w * 32][0]);
                GLOAD_LDS16(gB1 + k0, &sB[cur ^ 1][w * 32 + 16][0]);
                asm volatile("s_waitcnt vmcnt(3)" ::: "memory");
            } else {
                asm volatile("s_waitcnt vmcnt(0)" ::: "memory");
            }
            __builtin_amdgcn_s_barrier();   // all waves' cur-tile loads landed

            bf16x8 a[4], bg[2], bu[2];
            #pragma unroll
            for (int i = 0; i < 4; i++)
                a[i] = *(const bf16x8*)&sA[cur][wm * 64 + i * 16 + l15][rg];
            #pragma unroll
            for (int j = 0; j < 2; j++) {
                bg[j] = *(const bf16x8*)&sB[cur][wn * 32 + j * 16 + l15][rg];
                bu[j] = *(const bf16x8*)&sB[cur][128 + wn * 32 + j * 16 + l15][rg];
            }
            #pragma unroll
            for (int i = 0; i < 4; i++)
                #pragma unroll
                for (int j = 0; j < 2; j++) {
                    acc[i][j]     = __builtin_amdgcn_mfma_f32_16x16x32_bf16(a[i], bg[j], acc[i][j], 0, 0, 0);
                    acc[i][2 + j] = __builtin_amdgcn_mfma_f32_16x16x32_bf16(a[i], bu[j], acc[i][2 + j], 0, 0, 0);
                }
            __builtin_amdgcn_sched_barrier(0);  // keep MFMAs before barrier
            __builtin_amdgcn_s_barrier();       // cur reusable for next stage
        }

        // epilogue: act = silu(gate) * up
        #pragma unroll
        for (int i = 0; i < 4; i++) {
            #pragma unroll
            for (int rr = 0; rr < 4; rr++) {
                int m = m0 + wm * 64 + i * 16 + lg * 4 + rr;
                if (m < mend) {
                    #pragma unroll
                    for (int j = 0; j < 2; j++) {
                        float gv = acc[i][j][rr];
                        float uv = acc[i][2 + j][rr];
                        float sv = gv / (1.f + __expf(-gv));
                        act[(size_t)m * I_DIM + c0 + wn * 32 + j * 16 + l15] = (bf16_t)(sv * uv);
                    }
                }
            }
        }
    }
}

// ---------------------------------------------------------------- GEMM2 (+ scale, k-split x4)
// R8 engine; kz = 4 K-slices of 512 -> nit = n_slots*16 (~528) fills the
// resident-block slots.
__global__ __launch_bounds__(512, 4)
void gemm2_kernel(const bf16_t* __restrict__ act,
                  const bf16_t* __restrict__ w2bf,
                  const int* __restrict__ offsets,
                  const int* __restrict__ tile_e,
                  const int* __restrict__ tile_m0,
                  const int* __restrict__ n_slots,
                  const int* __restrict__ pair_dst,
                  const float* __restrict__ pair_wt,
                  bf16_t* __restrict__ ybuf) {
    __shared__ __align__(16) bf16_t sA[2][128][32];
    __shared__ __align__(16) bf16_t sB[2][256][32];

    int tid = threadIdx.x;
    int lane = tid & 63, w = tid >> 6;
    int wm = w >> 2, wn = w & 3;
    int l15 = lane & 15, lg = lane >> 4;
    int sr = lane >> 2, sg = lane & 3;
    int gcol = (sg ^ (sr & 3)) * 8;
    int rg   = (lg ^ (l15 & 3)) * 8;

    int nit = *n_slots * 16;   // 4 n0-groups x 4 kz
    for (int it = blockIdx.x; it < nit; it += gridDim.x) {
        int slot = it >> 4;
        int n0   = ((it >> 2) & 3) << 8;   // out cols [n0, n0+256)
        int kz   = it & 3;
        int kb   = kz << 9;                // k-slice base (512)
        int e    = tile_e[slot];
        int m0   = tile_m0[slot];
        int mend = offsets[e + 1];
        const bf16_t* w2e = w2bf + (size_t)e * H_DIM * I_DIM;

        // rows >= mend read neighbor arena data (masked at epilogue)
        const bf16_t* gA0 = act + (size_t)(m0 + w * 16 + sr) * I_DIM + kb + gcol;
        const bf16_t* gB0 = w2e + (size_t)(n0 + w * 32 + sr) * I_DIM + kb + gcol;
        const bf16_t* gB1 = w2e + (size_t)(n0 + w * 32 + 16 + sr) * I_DIM + kb + gcol;

        f32x4 acc[4][4];
        #pragma unroll
        for (int i = 0; i < 4; i++)
            #pragma unroll
            for (int j = 0; j < 4; j++) acc[i][j] = zero4();

        GLOAD_LDS16(gA0, &sA[0][w * 16][0]);
        GLOAD_LDS16(gB0, &sB[0][w * 32][0]);
        GLOAD_LDS16(gB1, &sB[0][w * 32 + 16][0]);

        for (int t = 0; t < 16; t++) {     // K-slice 512 = 16 steps
            int cur = t & 1;
            if (t < 15) {
                int k0 = (t + 1) * 32;
                GLOAD_LDS16(gA0 + k0, &sA[cur ^ 1][w * 16][0]);
                GLOAD_LDS16(gB0 + k0, &sB[cur ^ 1][w * 32][0]);
                GLOAD_LDS16(gB1 + k0, &sB[cur ^ 1][w * 32 + 16][0]);
                asm volatile("s_waitcnt vmcnt(3)" ::: "memory");
            } else {
                asm volatile("s_waitcnt vmcnt(0)" ::: "memory");
            }
            __builtin_amdgcn_s_barrier();

            bf16x8 a[4], b[4];
            #pragma unroll
            for (int i = 0; i < 4; i++)
                a[i] = *(const bf16x8*)&sA[cur][wm * 64 + i * 16 + l15][rg];
            #pragma unroll
            for (int j = 0; j < 4; j++)
                b[j] = *(const bf16x8*)&sB[cur][wn * 64 + j * 16 + l15][rg];
            #pragma unroll
            for (int i = 0; i < 4; i++)
                #pragma unroll
                for (int j = 0; j < 4; j++)
                    acc[i][j] = __builtin_amdgcn_mfma_f32_16x16x32_bf16(a[i], b[j], acc[i][j], 0, 0, 0);
            __builtin_amdgcn_sched_barrier(0);
            __builtin_amdgcn_s_barrier();
        }

        bf16_t* ybufz = ybuf + (size_t)kz * P_MAX * H_DIM;
        #pragma unroll
        for (int i = 0; i < 4; i++) {
            #pragma unroll
            for (int rr = 0; rr < 4; rr++) {
                int m = m0 + wm * 64 + i * 16 + lg * 4 + rr;
                if (m < mend) {
                    int   dst = pair_dst[m];
                    float wv  = pair_wt[m];
                    #pragma unroll
                    for (int j = 0; j < 4; j++)
                        ybufz[(size_t)dst * H_DIM + n0 + wn * 64 + j * 16 + l15] =
                            (bf16_t)(acc[i][j][rr] * wv);
                }
            }
        }
    }
}

// ---------------------------------------------------------------- combine
// ybuf bf16, 4 kz-slices x 2 pairs: sum 8 bf16x8 in f32, write 8 f32.
__global__ void combine_kernel(const bf16_t* __restrict__ ybuf,
                               float* __restrict__ out) {
    int idx = blockIdx.x * 256 + threadIdx.x;   // one 8-elem chunk each
    int t = idx >> 7;                           // 128 chunks per token row
    int h = (idx & 127) * 8;
    const size_t SL = (size_t)P_MAX * H_DIM;
    float s[8];
    #pragma unroll
    for (int j = 0; j < 8; j++) s[j] = 0.f;
    #pragma unroll
    for (int kz = 0; kz < 4; kz++) {
        bf16x8 y0 = *(const bf16x8*)(ybuf + kz * SL + (size_t)(t * 2)     * H_DIM + h);
        bf16x8 y1 = *(const bf16x8*)(ybuf + kz * SL + (size_t)(t * 2 + 1) * H_DIM + h);
        #pragma unroll
        for (int j = 0; j < 8; j++) s[j] += (float)y0[j] + (float)y1[j];
    }
    f32x4 o0, o1;
    #pragma unroll
    for (int j = 0; j < 4; j++) { o0[j] = s[j]; o1[j] = s[4 + j]; }
    *(f32x4*)(out + (size_t)t * H_DIM + h)     = o0;
    *(f32x4*)(out + (size_t)t * H_DIM + h + 4) = o1;
}

// ---------------------------------------------------------------- launch
extern "C" void kernel_launch(void* const* d_in, const int* in_sizes, int n_in,
                              void* d_out, int out_size, void* d_ws, size_t ws_size,
                              hipStream_t stream) {
    const float* hidden = (const float*)d_in[0];
    const float* w1     = (const float*)d_in[1];
    const float* w2     = (const float*)d_in[2];
    const float* gating = (const float*)d_in[3];
    float* out = (float*)d_out;

    const size_t N0 = (size_t)T_TOK * H_DIM;             // hidden elems
    const size_t N1 = (size_t)E_NUM * 2 * I_DIM * H_DIM; // w1 elems
    const size_t N2 = (size_t)E_NUM * H_DIM * I_DIM;     // w2 elems

    char* ws = (char*)d_ws;
    size_t off = 0;
    auto alloc = [&](size_t bytes) -> void* {
        void* p = ws + off;
        off += (bytes + 255) & ~(size_t)255;
        return p;
    };
    // order matters: act must not be last (gemm2 A-staging over-reads <=260KB)
    bf16_t* ybuf  = (bf16_t*)alloc((size_t)4 * P_MAX * H_DIM * sizeof(bf16_t));   // 33.6 MB (4 slices)
    bf16_t* act   = (bf16_t*)alloc((size_t)P_MAX * I_DIM * sizeof(bf16_t));       // 16.8 MB
    bf16_t* hbf   = (bf16_t*)alloc(N0 * sizeof(bf16_t));                          //  4.2 MB
    bf16_t* w1bf  = (bf16_t*)alloc(N1 * sizeof(bf16_t));                          // 67.1 MB
    bf16_t* w2bf  = (bf16_t*)alloc(N2 * sizeof(bf16_t));                          // 33.6 MB
    int*    pair_token = (int*)alloc(P_MAX * sizeof(int));
    int*    pair_dst   = (int*)alloc(P_MAX * sizeof(int));
    float*  pair_wt    = (float*)alloc(P_MAX * sizeof(float));
    int*    offsets    = (int*)alloc((E_NUM + 1) * sizeof(int));
    int*    n_slots    = (int*)alloc(sizeof(int));
    int*    tile_e     = (int*)alloc(MAX_SLOTS * sizeof(int));
    int*    tile_m0    = (int*)alloc(MAX_SLOTS * sizeof(int));

    int conv_blocks = (int)((N0 + N1) / (256 * 16));   // 8704
    convert_route_kernel<<<conv_blocks + 1, 256, 0, stream>>>(
        hidden, w1, gating, hbf, w1bf,
        offsets, tile_e, tile_m0, n_slots, pair_token, pair_dst, pair_wt);
    gemm1_kernel<<<CONV_BLKS + 768, 512, 0, stream>>>(
        hbf, w1bf, w2, w2bf, pair_token, offsets, tile_e, tile_m0, n_slots, act);
    gemm2_kernel<<<768, 512, 0, stream>>>(
        act, w2bf, offsets, tile_e, tile_m0, n_slots, pair_dst, pair_wt, ybuf);
    combine_kernel<<<(T_TOK * H_DIM / 8) / 256, 256, 0, stream>>>(ybuf, out);

    (void)in_sizes; (void)n_in; (void)out_size; (void)ws_size;
}

// Round 23
// 147.155 us; speedup vs baseline: 1.4060x; 1.0550x over previous
//
#include <hip/hip_runtime.h>
#include <hip/hip_bf16.h>
#include <math.h>

// Problem constants (fixed by the reference file)
#define T_TOK 2048
#define H_DIM 1024
#define I_DIM 2048
#define E_NUM 8
#define TOPK  2
#define P_MAX (T_TOK * TOPK)   // 4096 (token, k) pairs
#define MAX_SLOTS 40           // max 128-row slots: 4096/128 + 8
#define CONV_BLKS 128          // gemm1-fused w2-convert blocks

typedef __bf16 bf16_t;
typedef __attribute__((ext_vector_type(8))) __bf16 bf16x8;
typedef __attribute__((ext_vector_type(4))) float  f32x4;

// global_load_lds: per-lane GLOBAL address, wave-uniform LDS base; lane n
// writes lds_base + n*16 bytes (m104/m108).
#define GLOAD_LDS16(gptr, lptr)                                                   \
    __builtin_amdgcn_global_load_lds(                                             \
        (const __attribute__((address_space(1))) void*)(gptr),                    \
        (__attribute__((address_space(3))) void*)(lptr), 16, 0, 0)

__device__ inline f32x4 zero4() {
    f32x4 z; z[0] = 0.f; z[1] = 0.f; z[2] = 0.f; z[3] = 0.f; return z;
}

__device__ inline bf16x8 cvt8(f32x4 a, f32x4 b) {
    bf16x8 o;
    o[0] = (bf16_t)a[0]; o[1] = (bf16_t)a[1]; o[2] = (bf16_t)a[2]; o[3] = (bf16_t)a[3];
    o[4] = (bf16_t)b[0]; o[5] = (bf16_t)b[1]; o[6] = (bf16_t)b[2]; o[7] = (bf16_t)b[3];
    return o;
}

// ---------------------------------------------------------------- convert + fused routing
// Block 0: full routing chain (router -> scan -> scatter) with
// __syncthreads phase ordering; 256 thr x 8 tokens each, top-2 state held
// in registers between phases, counts/cursor in LDS. Blocks >= 1: f32->bf16
// convert of hidden + w1 (one 16-elem chunk per thread).
__global__ __launch_bounds__(256)
void convert_route_kernel(const float* __restrict__ hidden,
                          const float* __restrict__ w1,
                          const float* __restrict__ gating,
                          bf16_t* __restrict__ hbf,
                          bf16_t* __restrict__ w1bf,
                          int* __restrict__ offsets,      // [E_NUM+1]
                          int* __restrict__ tile_e,
                          int* __restrict__ tile_m0,
                          int* __restrict__ n_slots,
                          int* __restrict__ pair_token,
                          int* __restrict__ pair_dst,
                          float* __restrict__ pair_wt) {
    const size_t N0 = (size_t)T_TOK * H_DIM;
    int tid = threadIdx.x;

    if (blockIdx.x == 0) {   // ---- routing role
        __shared__ int cnt[E_NUM];
        __shared__ int cur[E_NUM];
        __shared__ int offs[E_NUM + 1];
        if (tid < E_NUM) { cnt[tid] = 0; cur[tid] = 0; }
        __syncthreads();

        int   id0[8], id1[8];
        float wt0[8], wt1[8];
        #pragma unroll
        for (int q = 0; q < 8; q++) {
            int t = tid * 8 + q;
            float l[E_NUM];
            float m = -1e30f;
            #pragma unroll
            for (int e = 0; e < E_NUM; e++) { l[e] = gating[t * E_NUM + e]; m = fmaxf(m, l[e]); }
            float p[E_NUM];
            #pragma unroll
            for (int e = 0; e < E_NUM; e++) p[e] = __expf(l[e] - m);
            int i0 = 0; float p0 = p[0];
            #pragma unroll
            for (int e = 1; e < E_NUM; e++) if (p[e] > p0) { p0 = p[e]; i0 = e; }
            int i1 = -1; float p1 = -1.f;
            #pragma unroll
            for (int e = 0; e < E_NUM; e++) if (e != i0 && p[e] > p1) { p1 = p[e]; i1 = e; }
            float inv = 1.f / (p0 + p1);
            id0[q] = i0; wt0[q] = p0 * inv;
            id1[q] = i1; wt1[q] = p1 * inv;
            atomicAdd(&cnt[i0], 1);
            atomicAdd(&cnt[i1], 1);
        }
        __syncthreads();

        if (tid == 0) {   // scan + tile map
            int off = 0;
            for (int e = 0; e < E_NUM; e++) { offs[e] = off; offsets[e] = off; off += cnt[e]; }
            offs[E_NUM] = off; offsets[E_NUM] = off;
            int s = 0;
            for (int e = 0; e < E_NUM; e++)
                for (int m0 = offs[e]; m0 < offs[e + 1]; m0 += 128) {
                    tile_e[s] = e; tile_m0[s] = m0; s++;
                }
            *n_slots = s;
        }
        __syncthreads();

        #pragma unroll
        for (int q = 0; q < 8; q++) {   // scatter
            int t = tid * 8 + q;
            int p0 = offs[id0[q]] + atomicAdd(&cur[id0[q]], 1);
            pair_token[p0] = t; pair_dst[p0] = t * 2;     pair_wt[p0] = wt0[q];
            int p1 = offs[id1[q]] + atomicAdd(&cur[id1[q]], 1);
            pair_token[p1] = t; pair_dst[p1] = t * 2 + 1; pair_wt[p1] = wt1[q];
        }
        return;
    }

    // ---- convert role (hidden ++ w1, one 16-elem chunk per thread)
    size_t g = (size_t)(blockIdx.x - 1) * 256 + tid;
    size_t i = g * 16;
    const float* src; bf16_t* dst; size_t o;
    if (i < N0) { src = hidden; dst = hbf;  o = i; }
    else        { src = w1;     dst = w1bf; o = i - N0; }
    f32x4 v0 = *(const f32x4*)(src + o);
    f32x4 v1 = *(const f32x4*)(src + o + 4);
    f32x4 v2 = *(const f32x4*)(src + o + 8);
    f32x4 v3 = *(const f32x4*)(src + o + 12);
    *(bf16x8*)(dst + o)     = cvt8(v0, v1);
    *(bf16x8*)(dst + o + 8) = cvt8(v2, v3);
}

// ---------------------------------------------------------------- GEMM1 + SwiGLU (+ fused w2 convert)
// R8 counted-vmcnt engine, TRIPLE-buffered LDS -> ONE barrier per K-step.
// With 3 buffers the WAR gap is 2 steps: fastest wave (<=1 barrier ahead)
// stages buf[(t+2)%3] while slowest reads buf[t%3] -> disjoint, so the
// post-MFMA barrier is dropped. Per-wave vmcnt(3) before the barrier
// proves own stage(t) landed; the barrier proves all waves'.
// Blocks [0, CONV_BLKS): w2 f32->bf16 convert role (streams under gemm1).
__global__ __launch_bounds__(512, 4)
void gemm1_kernel(const bf16_t* __restrict__ hbf,
                  const bf16_t* __restrict__ w1bf,
                  const float* __restrict__ w2,
                  bf16_t* __restrict__ w2bf,
                  const int* __restrict__ pair_token,
                  const int* __restrict__ offsets,
                  const int* __restrict__ tile_e,
                  const int* __restrict__ tile_m0,
                  const int* __restrict__ n_slots,
                  bf16_t* __restrict__ act) {
    __shared__ __align__(16) bf16_t sA[3][128][32];  // 24 KB
    __shared__ __align__(16) bf16_t sB[3][256][32];  // 48 KB

    int tid = threadIdx.x;

    if (blockIdx.x < CONV_BLKS) {   // ---- w2 convert role
        const size_t N2c = (size_t)E_NUM * H_DIM * I_DIM / 16;  // 16-elem chunks
        size_t stride = (size_t)CONV_BLKS * 512;
        for (size_t g = (size_t)blockIdx.x * 512 + tid; g < N2c; g += stride) {
            size_t i = g * 16;
            f32x4 v0 = *(const f32x4*)(w2 + i);
            f32x4 v1 = *(const f32x4*)(w2 + i + 4);
            f32x4 v2 = *(const f32x4*)(w2 + i + 8);
            f32x4 v3 = *(const f32x4*)(w2 + i + 12);
            *(bf16x8*)(w2bf + i)     = cvt8(v0, v1);
            *(bf16x8*)(w2bf + i + 8) = cvt8(v2, v3);
        }
        return;
    }

    int lane = tid & 63, w = tid >> 6;     // 8 waves
    int wm = w >> 2, wn = w & 3;           // 2M x 4N
    int l15 = lane & 15, lg = lane >> 4;
    int sr = lane >> 2, sg = lane & 3;     // staging sub-row / granule
    int gcol = (sg ^ (sr & 3)) * 8;        // inverse-swizzled SOURCE granule
    int rg   = (lg ^ (l15 & 3)) * 8;       // swizzled READ granule

    int nit = *n_slots * 16;
    for (int it = blockIdx.x - CONV_BLKS; it < nit; it += gridDim.x - CONV_BLKS) {
        int slot = it >> 4;
        int c0   = (it & 15) << 7;         // act cols [c0, c0+128)
        int e    = tile_e[slot];
        int m0   = tile_m0[slot];
        int mend = offsets[e + 1];
        const bf16_t* w1e = w1bf + (size_t)e * (2 * I_DIM) * H_DIM;

        // staging addresses (k0 added in loop)
        int parow = m0 + w * 16 + sr;
        int tok = (parow < mend) ? pair_token[parow] : 0;  // dummy, masked later
        const bf16_t* gA0 = hbf + (size_t)tok * H_DIM + gcol;
        int br0 = w * 32 + sr, br1 = br0 + 16;
        int wr0 = (br0 < 128) ? (c0 + br0) : (I_DIM + c0 + br0 - 128);
        int wr1 = (br1 < 128) ? (c0 + br1) : (I_DIM + c0 + br1 - 128);
        const bf16_t* gB0 = w1e + (size_t)wr0 * H_DIM + gcol;
        const bf16_t* gB1 = w1e + (size_t)wr1 * H_DIM + gcol;

        f32x4 acc[4][4];  // j=0,1 gate; j=2,3 up
        #pragma unroll
        for (int i = 0; i < 4; i++)
            #pragma unroll
            for (int j = 0; j < 4; j++) acc[i][j] = zero4();

        // prologue: stage K-step 0 into buf 0
        GLOAD_LDS16(gA0, &sA[0][w * 16][0]);
        GLOAD_LDS16(gB0, &sB[0][w * 32][0]);
        GLOAD_LDS16(gB1, &sB[0][w * 32 + 16][0]);

        int cur = 0, nxt = 1;
        for (int t = 0; t < 32; t++) {
            if (t < 31) {
                int k0 = (t + 1) * 32;
                GLOAD_LDS16(gA0 + k0, &sA[nxt][w * 16][0]);
                GLOAD_LDS16(gB0 + k0, &sB[nxt][w * 32][0]);
                GLOAD_LDS16(gB1 + k0, &sB[nxt][w * 32 + 16][0]);
                asm volatile("s_waitcnt vmcnt(3)" ::: "memory");  // own stage(t) landed
            } else {
                asm volatile("s_waitcnt vmcnt(0)" ::: "memory");
            }
            __builtin_amdgcn_s_barrier();   // all waves' stage(t) landed

            bf16x8 a[4], bg[2], bu[2];
            #pragma unroll
            for (int i = 0; i < 4; i++)
                a[i] = *(const bf16x8*)&sA[cur][wm * 64 + i * 16 + l15][rg];
            #pragma unroll
            for (int j = 0; j < 2; j++) {
                bg[j] = *(const bf16x8*)&sB[cur][wn * 32 + j * 16 + l15][rg];
                bu[j] = *(const bf16x8*)&sB[cur][128 + wn * 32 + j * 16 + l15][rg];
            }
            #pragma unroll
            for (int i = 0; i < 4; i++)
                #pragma unroll
                for (int j = 0; j < 2; j++) {
                    acc[i][j]     = __builtin_amdgcn_mfma_f32_16x16x32_bf16(a[i], bg[j], acc[i][j], 0, 0, 0);
                    acc[i][2 + j] = __builtin_amdgcn_mfma_f32_16x16x32_bf16(a[i], bu[j], acc[i][2 + j], 0, 0, 0);
                }
            cur = (cur == 2) ? 0 : cur + 1;
            nxt = (nxt == 2) ? 0 : nxt + 1;
        }

        // epilogue: act = silu(gate) * up
        #pragma unroll
        for (int i = 0; i < 4; i++) {
            #pragma unroll
            for (int rr = 0; rr < 4; rr++) {
                int m = m0 + wm * 64 + i * 16 + lg * 4 + rr;
                if (m < mend) {
                    #pragma unroll
                    for (int j = 0; j < 2; j++) {
                        float gv = acc[i][j][rr];
                        float uv = acc[i][2 + j][rr];
                        float sv = gv / (1.f + __expf(-gv));
                        act[(size_t)m * I_DIM + c0 + wn * 32 + j * 16 + l15] = (bf16_t)(sv * uv);
                    }
                }
            }
        }
    }
}

// ---------------------------------------------------------------- GEMM2 (+ scale, k-split x4)
// Same triple-buffered single-barrier engine; kz = 4 K-slices of 512.
__global__ __launch_bounds__(512, 4)
void gemm2_kernel(const bf16_t* __restrict__ act,
                  const bf16_t* __restrict__ w2bf,
                  const int* __restrict__ offsets,
                  const int* __restrict__ tile_e,
                  const int* __restrict__ tile_m0,
                  const int* __restrict__ n_slots,
                  const int* __restrict__ pair_dst,
                  const float* __restrict__ pair_wt,
                  bf16_t* __restrict__ ybuf) {
    __shared__ __align__(16) bf16_t sA[3][128][32];
    __shared__ __align__(16) bf16_t sB[3][256][32];

    int tid = threadIdx.x;
    int lane = tid & 63, w = tid >> 6;
    int wm = w >> 2, wn = w & 3;
    int l15 = lane & 15, lg = lane >> 4;
    int sr = lane >> 2, sg = lane & 3;
    int gcol = (sg ^ (sr & 3)) * 8;
    int rg   = (lg ^ (l15 & 3)) * 8;

    int nit = *n_slots * 16;   // 4 n0-groups x 4 kz
    for (int it = blockIdx.x; it < nit; it += gridDim.x) {
        int slot = it >> 4;
        int n0   = ((it >> 2) & 3) << 8;   // out cols [n0, n0+256)
        int kz   = it & 3;
        int kb   = kz << 9;                // k-slice base (512)
        int e    = tile_e[slot];
        int m0   = tile_m0[slot];
        int mend = offsets[e + 1];
        const bf16_t* w2e = w2bf + (size_t)e * H_DIM * I_DIM;

        // rows >= mend read neighbor arena data (masked at epilogue)
        const bf16_t* gA0 = act + (size_t)(m0 + w * 16 + sr) * I_DIM + kb + gcol;
        const bf16_t* gB0 = w2e + (size_t)(n0 + w * 32 + sr) * I_DIM + kb + gcol;
        const bf16_t* gB1 = w2e + (size_t)(n0 + w * 32 + 16 + sr) * I_DIM + kb + gcol;

        f32x4 acc[4][4];
        #pragma unroll
        for (int i = 0; i < 4; i++)
            #pragma unroll
            for (int j = 0; j < 4; j++) acc[i][j] = zero4();

        GLOAD_LDS16(gA0, &sA[0][w * 16][0]);
        GLOAD_LDS16(gB0, &sB[0][w * 32][0]);
        GLOAD_LDS16(gB1, &sB[0][w * 32 + 16][0]);

        int cur = 0, nxt = 1;
        for (int t = 0; t < 16; t++) {     // K-slice 512 = 16 steps
            if (t < 15) {
                int k0 = (t + 1) * 32;
                GLOAD_LDS16(gA0 + k0, &sA[nxt][w * 16][0]);
                GLOAD_LDS16(gB0 + k0, &sB[nxt][w * 32][0]);
                GLOAD_LDS16(gB1 + k0, &sB[nxt][w * 32 + 16][0]);
                asm volatile("s_waitcnt vmcnt(3)" ::: "memory");
            } else {
                asm volatile("s_waitcnt vmcnt(0)" ::: "memory");
            }
            __builtin_amdgcn_s_barrier();

            bf16x8 a[4], b[4];
            #pragma unroll
            for (int i = 0; i < 4; i++)
                a[i] = *(const bf16x8*)&sA[cur][wm * 64 + i * 16 + l15][rg];
            #pragma unroll
            for (int j = 0; j < 4; j++)
                b[j] = *(const bf16x8*)&sB[cur][wn * 64 + j * 16 + l15][rg];
            #pragma unroll
            for (int i = 0; i < 4; i++)
                #pragma unroll
                for (int j = 0; j < 4; j++)
                    acc[i][j] = __builtin_amdgcn_mfma_f32_16x16x32_bf16(a[i], b[j], acc[i][j], 0, 0, 0);
            cur = (cur == 2) ? 0 : cur + 1;
            nxt = (nxt == 2) ? 0 : nxt + 1;
        }

        bf16_t* ybufz = ybuf + (size_t)kz * P_MAX * H_DIM;
        #pragma unroll
        for (int i = 0; i < 4; i++) {
            #pragma unroll
            for (int rr = 0; rr < 4; rr++) {
                int m = m0 + wm * 64 + i * 16 + lg * 4 + rr;
                if (m < mend) {
                    int   dst = pair_dst[m];
                    float wv  = pair_wt[m];
                    #pragma unroll
                    for (int j = 0; j < 4; j++)
                        ybufz[(size_t)dst * H_DIM + n0 + wn * 64 + j * 16 + l15] =
                            (bf16_t)(acc[i][j][rr] * wv);
                }
            }
        }
    }
}

// ---------------------------------------------------------------- combine
// ybuf bf16, 4 kz-slices x 2 pairs: sum 8 bf16x8 in f32, write 8 f32.
__global__ void combine_kernel(const bf16_t* __restrict__ ybuf,
                               float* __restrict__ out) {
    int idx = blockIdx.x * 256 + threadIdx.x;   // one 8-elem chunk each
    int t = idx >> 7;                           // 128 chunks per token row
    int h = (idx & 127) * 8;
    const size_t SL = (size_t)P_MAX * H_DIM;
    float s[8];
    #pragma unroll
    for (int j = 0; j < 8; j++) s[j] = 0.f;
    #pragma unroll
    for (int kz = 0; kz < 4; kz++) {
        bf16x8 y0 = *(const bf16x8*)(ybuf + kz * SL + (size_t)(t * 2)     * H_DIM + h);
        bf16x8 y1 = *(const bf16x8*)(ybuf + kz * SL + (size_t)(t * 2 + 1) * H_DIM + h);
        #pragma unroll
        for (int j = 0; j < 8; j++) s[j] += (float)y0[j] + (float)y1[j];
    }
    f32x4 o0, o1;
    #pragma unroll
    for (int j = 0; j < 4; j++) { o0[j] = s[j]; o1[j] = s[4 + j]; }
    *(f32x4*)(out + (size_t)t * H_DIM + h)     = o0;
    *(f32x4*)(out + (size_t)t * H_DIM + h + 4) = o1;
}

// ---------------------------------------------------------------- launch
extern "C" void kernel_launch(void* const* d_in, const int* in_sizes, int n_in,
                              void* d_out, int out_size, void* d_ws, size_t ws_size,
                              hipStream_t stream) {
    const float* hidden = (const float*)d_in[0];
    const float* w1     = (const float*)d_in[1];
    const float* w2     = (const float*)d_in[2];
    const float* gating = (const float*)d_in[3];
    float* out = (float*)d_out;

    const size_t N0 = (size_t)T_TOK * H_DIM;             // hidden elems
    const size_t N1 = (size_t)E_NUM * 2 * I_DIM * H_DIM; // w1 elems
    const size_t N2 = (size_t)E_NUM * H_DIM * I_DIM;     // w2 elems

    char* ws = (char*)d_ws;
    size_t off = 0;
    auto alloc = [&](size_t bytes) -> void* {
        void* p = ws + off;
        off += (bytes + 255) & ~(size_t)255;
        return p;
    };
    // order matters: act must not be last (gemm2 A-staging over-reads <=260KB)
    bf16_t* ybuf  = (bf16_t*)alloc((size_t)4 * P_MAX * H_DIM * sizeof(bf16_t));   // 33.6 MB (4 slices)
    bf16_t* act   = (bf16_t*)alloc((size_t)P_MAX * I_DIM * sizeof(bf16_t));       // 16.8 MB
    bf16_t* hbf   = (bf16_t*)alloc(N0 * sizeof(bf16_t));                          //  4.2 MB
    bf16_t* w1bf  = (bf16_t*)alloc(N1 * sizeof(bf16_t));                          // 67.1 MB
    bf16_t* w2bf  = (bf16_t*)alloc(N2 * sizeof(bf16_t));                          // 33.6 MB
    int*    pair_token = (int*)alloc(P_MAX * sizeof(int));
    int*    pair_dst   = (int*)alloc(P_MAX * sizeof(int));
    float*  pair_wt    = (float*)alloc(P_MAX * sizeof(float));
    int*    offsets    = (int*)alloc((E_NUM + 1) * sizeof(int));
    int*    n_slots    = (int*)alloc(sizeof(int));
    int*    tile_e     = (int*)alloc(MAX_SLOTS * sizeof(int));
    int*    tile_m0    = (int*)alloc(MAX_SLOTS * sizeof(int));

    int conv_blocks = (int)((N0 + N1) / (256 * 16));   // 8704
    convert_route_kernel<<<conv_blocks + 1, 256, 0, stream>>>(
        hidden, w1, gating, hbf, w1bf,
        offsets, tile_e, tile_m0, n_slots, pair_token, pair_dst, pair_wt);
    gemm1_kernel<<<CONV_BLKS + 768, 512, 0, stream>>>(
        hbf, w1bf, w2, w2bf, pair_token, offsets, tile_e, tile_m0, n_slots, act);
    gemm2_kernel<<<768, 512, 0, stream>>>(
        act, w2bf, offsets, tile_e, tile_m0, n_slots, pair_dst, pair_wt, ybuf);
    combine_kernel<<<(T_TOK * H_DIM / 8) / 256, 256, 0, stream>>>(ybuf, out);

    (void)in_sizes; (void)n_in; (void)out_size; (void)ws_size;
}